// Round 9
// baseline (14160.146 us; speedup 1.0000x reference)
//
#include <hip/hip_runtime.h>
#include <math.h>

// NSE B=32 L=1024 K=256 — persistent kernel R9.
// vs R8: AR 776->780 dwords (b-lane stride 195 float4 ≡ 3 mod 8 -> matvec arena
// reads conflict-free per 8-lane phase); rotations dropped; phase-A pass-2 uses
// register-cached updated mem rows (no LDS re-read).

#define Bb 32
#define LL 1024
#define KK 256
#define AR 780     // arena stride (dwords): 195 float4s, mod 8 = 3 -> conflict-free
#define ASCOPE __HIP_MEMORY_SCOPE_AGENT
#define FSTR 16

__device__ __forceinline__ float sigf(float v) { return 1.0f / (1.0f + __expf(-v)); }

__device__ __forceinline__ void st_coh2(float* p, float a, float b) {
    float2 v = make_float2(a, b);
    __hip_atomic_store((unsigned long long*)p,
                       __builtin_bit_cast(unsigned long long, v),
                       __ATOMIC_RELAXED, ASCOPE);
}
__device__ __forceinline__ float2 ld_coh2(const float* p) {
    unsigned long long u = __hip_atomic_load((const unsigned long long*)p,
                                             __ATOMIC_RELAXED, ASCOPE);
    return __builtin_bit_cast(float2, u);
}

__device__ __forceinline__ void bar_arrive(unsigned* fown, unsigned val) {
    asm volatile("s_waitcnt vmcnt(0) lgkmcnt(0)" ::: "memory");
    __syncthreads();
    if (threadIdx.x == 0)
        __hip_atomic_store(fown, val, __ATOMIC_RELAXED, ASCOPE);
}
__device__ __forceinline__ void bar_wait(unsigned* fbase, unsigned val) {
    if (threadIdx.x < 64) {
        for (;;) {
            unsigned v = __hip_atomic_load(fbase + threadIdx.x * FSTR,
                                           __ATOMIC_RELAXED, ASCOPE);
            if (__all(v >= val)) break;
            __builtin_amdgcn_s_sleep(1);
        }
    }
    asm volatile("" ::: "memory");
    __syncthreads();
}

// ---------------- one-time precompute (unchanged) ----------------
__global__ __launch_bounds__(256) void k_pre(
    const float* __restrict__ cW, const float* __restrict__ cb,
    const float* __restrict__ wWx, const float* __restrict__ wb,
    const float* __restrict__ rWx, const float* __restrict__ rWh,
    const float* __restrict__ wWh,
    float* __restrict__ WfT, float* __restrict__ rWT, float* __restrict__ bfv,
    unsigned* __restrict__ flg) {
    int bid = blockIdx.x, tid = threadIdx.x;
    if (bid < 512) {
        __shared__ float srow[512];
        srow[tid] = cW[(size_t)bid * 512 + tid];
        srow[256 + tid] = cW[(size_t)bid * 512 + 256 + tid];
        __syncthreads();
#pragma unroll
        for (int rep = 0; rep < 4; rep++) {
            int col = rep * 256 + tid;
            float a = 0.f;
#pragma unroll 4
            for (int c = 0; c < 512; c++) a += srow[c] * wWx[(size_t)c * 1024 + col];
            WfT[(size_t)col * 768 + bid] = a;
        }
    } else if (bid < 516) {
        int col = (bid - 512) * 256 + tid;
        float a = wb[col];
#pragma unroll 4
        for (int c = 0; c < 512; c++) a += cb[c] * wWx[(size_t)c * 1024 + col];
        bfv[col] = a;
    } else if (bid < 644) {
        int k0 = (bid - 516) * 2;
        for (int kk = k0; kk < k0 + 2; kk++)
            for (int col = tid; col < 1024; col += 256)
                rWT[(size_t)col * 512 + kk] = rWx[(size_t)kk * 1024 + col];
    } else if (bid < 772) {
        int k0 = (bid - 644) * 2;
        for (int kk = k0; kk < k0 + 2; kk++)
            for (int col = tid; col < 1024; col += 256)
                rWT[(size_t)col * 512 + 256 + kk] = rWh[(size_t)kk * 1024 + col];
    } else if (bid < 900) {
        int k0 = (bid - 772) * 2;
        for (int kk = k0; kk < k0 + 2; kk++)
            for (int col = tid; col < 1024; col += 256)
                WfT[(size_t)col * 768 + 512 + kk] = wWh[(size_t)kk * 1024 + col];
    } else {
        int idx = (bid - 900) * 256 + tid;
        flg[idx] = 0u;
    }
}

// ---------------- persistent kernel ----------------
__global__ __launch_bounds__(512, 1) void k_nse(
    const float* __restrict__ x, const float* __restrict__ rb,
    const float* __restrict__ rWT, const float* __restrict__ WfT,
    const float* __restrict__ bfv, float* __restrict__ st,
    float* __restrict__ out, unsigned* __restrict__ flg) {
    __shared__ float smem[32768 + 8 * AR + 8 + 8 + 16 + 128 + 128 + 128];
    float* memT   = smem;                 // [128][256]
    float* arena  = smem + 32768;         // [8][AR]: x/m_rt[0,256) hr[256,512) hw[512,768)
    float* sMw    = arena + 8 * AR;       // 8
    float* sSw    = sMw + 8;              // 8
    float* sMS    = sSw + 8;              // [8][2] per-b (M,S)
    float* sScore = sMS + 16;             // [8][16]
    float* sGr    = sScore + 128;         // [16][8] reader gates
    float* sGw    = sGr + 128;            // [16][8] writer gates

    float* hrb[2] = { st, st + 8192 };
    float* hwb[2] = { st + 16384, st + 24576 };
    float* partMS = st + 32832;           // [256][2]
    float* partV  = st + 33344;           // [256][256]

    int g = blockIdx.x, tid = threadIdx.x;
    int w = tid >> 6, ln = tid & 63;
    int bA = g >> 3;                      // phase-A batch
    int bg = g >> 6, gl = g & 63;
    int j0 = gl * 4;
    unsigned* fA = flg + (bg * 64) * FSTR;
    unsigned* fB = flg + (256 + bg * 64) * FSTR;
    unsigned* fAo = fA + gl * FSTR;
    unsigned* fBo = fB + gl * FSTR;

    // matvec lane map: b in low 3 bits, ks 2 bits, cp 1 bit
    int bln = ln & 7, ks = (ln >> 3) & 3, cp = ln >> 5;
    int c = 2 * w + cp;                   // 0..15 block-local col
    int gate = c >> 2, jlc = c & 3;
    int col = gate * KK + j0 + jlc;
    int bglw = bg * 8 + w;                // this wave's staging/combine batch

    const float4* wfc = (const float4*)(WfT + (size_t)col * 768);
    const float4* rwc = (const float4*)(rWT + (size_t)col * 512);
    float4 w2[16];                        // m_rt rows (256..511) of col, ks slice
#pragma unroll
    for (int i = 0; i < 16; i++) w2[i] = wfc[64 + ks * 16 + i];

    float crreg = 0.f, cwreg = 0.f;       // cell states for (pb,pj) on wave0 tid<32

    // ---- prologue: memT <- x ; stage [x_0 | 0]; reader step 0 ----
    const float4* xsrc = (const float4*)(x + ((size_t)bA * LL + (size_t)(g & 7) * 128) * KK);
#pragma unroll
    for (int i = 0; i < 16; i++) ((float4*)memT)[tid + i * 512] = xsrc[tid + i * 512];
    ((float4*)(arena + w * AR))[ln] = ((const float4*)(x + (size_t)bglw * LL * KK))[ln];
    ((float4*)(arena + w * AR + 256))[ln] = make_float4(0.f, 0.f, 0.f, 0.f);
    __syncthreads();
    {
        float accr = 0.f;
        const float4* ain = (const float4*)(arena + bln * AR);
#pragma unroll 8
        for (int i = 0; i < 32; i++) {
            int idx = ks * 32 + i;
            float4 a = ain[idx], q = rwc[idx];
            accr += a.x * q.x + a.y * q.y + a.z * q.z + a.w * q.w;
        }
        accr += __shfl_xor(accr, 8);
        accr += __shfl_xor(accr, 16);
        if (!(ln & 24)) sGr[c * 8 + bln] = accr + rb[col];
    }
    __syncthreads();
    if (tid < 32) {
        int pb = tid & 7, pj = tid >> 3;
        int bgp = bg * 8 + pb;
        float gi = sGr[(0 + pj) * 8 + pb], gG = sGr[(8 + pj) * 8 + pb];
        float go = sGr[(12 + pj) * 8 + pb];
        float cn = sigf(gi) * tanhf(gG);
        float hn = sigf(go) * tanhf(cn);
        crreg = cn;
        float hn2 = __shfl(hn, tid + 8);
        if (!(pj & 1)) st_coh2(hrb[0] + bgp * KK + j0 + pj, hn, hn2);
    }
    bar_arrive(fBo, 1u);
    float4 xreg = ((const float4*)(x + ((size_t)bglw * LL + 1) * KK))[ln];
    bar_wait(fB, 1u);

    for (int t = 0; t < LL; t++) {
        int cur = t & 1, prv = cur ^ 1;
        // ===== A-top: issue MALL loads =====
        const float* hp = hrb[cur] + bA * KK + ln * 4;
        float2 ha = ld_coh2(hp), hc = ld_coh2(hp + 2);
        float4 h4 = make_float4(ha.x, ha.y, hc.x, hc.y);
        float4 hrs2, hws2, w4 = make_float4(0.f, 0.f, 0.f, 0.f);
        {
            const float* hq = hrb[cur] + bglw * KK + ln * 4;
            float2 a = ld_coh2(hq), cc = ld_coh2(hq + 2);
            hrs2 = make_float4(a.x, a.y, cc.x, cc.y);
        }
        float Mprev = 0.f, invS = 0.f;
        if (t > 0) {
            const float* wp0 = hwb[prv] + bA * KK + ln * 4;
            float2 wa = ld_coh2(wp0), wc = ld_coh2(wp0 + 2);
            w4 = make_float4(wa.x, wa.y, wc.x, wc.y);
            const float* hq = hwb[prv] + bglw * KK + ln * 4;
            float2 a = ld_coh2(hq), cc = ld_coh2(hq + 2);
            hws2 = make_float4(a.x, a.y, cc.x, cc.y);
            Mprev = sMS[(bA & 7) * 2];
            invS = 1.0f / sMS[(bA & 7) * 2 + 1];
        } else {
            hws2 = make_float4(0.f, 0.f, 0.f, 0.f);
        }
        // ===== phase A: update + dots, mem rows register-cached =====
        float dp[16];
        float4 v4c[16];
        float* rowp = memT + w * 16 * KK;
        if (t > 0) {
            float scs[16];
            const float4* sp = (const float4*)(sScore + w * 16);
#pragma unroll
            for (int q2 = 0; q2 < 4; q2++) {
                float4 s4 = sp[q2];
                scs[q2 * 4 + 0] = s4.x; scs[q2 * 4 + 1] = s4.y;
                scs[q2 * 4 + 2] = s4.z; scs[q2 * 4 + 3] = s4.w;
            }
#pragma unroll
            for (int i = 0; i < 16; i++) {
                float4* vp = (float4*)(rowp + i * KK) + ln;
                float4 v = *vp;
                float z = __expf(scs[i] - Mprev) * invS;
                float om = 1.0f - z;
                v.x = v.x * om + w4.x * z;
                v.y = v.y * om + w4.y * z;
                v.z = v.z * om + w4.z * z;
                v.w = v.w * om + w4.w * z;
                *vp = v;
                v4c[i] = v;
                dp[i] = h4.x * v.x + h4.y * v.y + h4.z * v.z + h4.w * v.w;
            }
        } else {
#pragma unroll
            for (int i = 0; i < 16; i++) {
                float4 v = *((float4*)(rowp + i * KK) + ln);
                v4c[i] = v;
                dp[i] = h4.x * v.x + h4.y * v.y + h4.z * v.z + h4.w * v.w;
            }
        }
        // ===== transpose-reduce, stride 9 (conflict-free) =====
        {
            float* sT = arena + w * AR;
            int rr = ln >> 3, kk2 = ln & 7;
#pragma unroll
            for (int hh = 0; hh < 2; hh++) {
                int o = hh * 8;
#pragma unroll
                for (int j = 0; j < 8; j++) sT[ln * 9 + j] = dp[o + j];
                float ps = 0.f;
#pragma unroll
                for (int j = 0; j < 8; j++) ps += sT[(j * 8 + kk2) * 9 + rr];
                ps += __shfl_xor(ps, 1);
                ps += __shfl_xor(ps, 2);
                ps += __shfl_xor(ps, 4);
                if (kk2 == 0) sScore[w * 16 + o + rr] = ps;
            }
        }
        // ===== softmax partials (mem rows from registers) =====
        {
            float scs2[16];
            const float4* sp = (const float4*)(sScore + w * 16);
#pragma unroll
            for (int q2 = 0; q2 < 4; q2++) {
                float4 s4 = sp[q2];
                scs2[q2 * 4 + 0] = s4.x; scs2[q2 * 4 + 1] = s4.y;
                scs2[q2 * 4 + 2] = s4.z; scs2[q2 * 4 + 3] = s4.w;
            }
            float M16 = scs2[0];
#pragma unroll
            for (int i = 1; i < 16; i++) M16 = fmaxf(M16, scs2[i]);
            float Sw = 0.f;
            float4 Vw = make_float4(0.f, 0.f, 0.f, 0.f);
#pragma unroll
            for (int i = 0; i < 16; i++) {
                float e = __expf(scs2[i] - M16);
                Sw += e;
                float4 v = v4c[i];
                Vw.x += e * v.x; Vw.y += e * v.y; Vw.z += e * v.z; Vw.w += e * v.w;
            }
            ((float4*)(arena + w * AR))[ln] = Vw;   // overwrites sT (reads done)
            if (ln == 0) { sMw[w] = M16; sSw[w] = Sw; }
        }
        __syncthreads();
        if (tid < 128) {
            float M = sMw[0];
#pragma unroll
            for (int q2 = 1; q2 < 8; q2++) M = fmaxf(M, sMw[q2]);
            float S = 0.f, V0 = 0.f, V1 = 0.f;
#pragma unroll
            for (int q2 = 0; q2 < 8; q2++) {
                float e = __expf(sMw[q2] - M);
                S += e * sSw[q2];
                V0 += e * arena[q2 * AR + 2 * tid];
                V1 += e * arena[q2 * AR + 2 * tid + 1];
            }
            st_coh2(partV + (size_t)g * KK + 2 * tid, V0, V1);
            if (tid == 0) st_coh2(partMS + g * 2, M, S);
        }
        bar_arrive(fAo, (unsigned)(t + 1));

        // ===== stage [x_{t+1} | hr_t | hw_{t-1}] into arena (per-wave b=bglw) =====
        if (t + 1 < LL) ((float4*)(arena + w * AR))[ln] = xreg;
        ((float4*)(arena + w * AR + 256))[ln] = hrs2;
        ((float4*)(arena + w * AR + 512))[ln] = hws2;
        __syncthreads();

        // ===== writer-pre stream: hr rows (fl4 64..127) + hw rows (fl4 128..191) =====
        float accw = (ks == 0) ? bfv[col] : 0.f;
        {
            const float4* ain = (const float4*)(arena + bln * AR);
#pragma unroll 8
            for (int i = 0; i < 16; i++) {
                int idx = ks * 16 + i;
                float4 a = ain[64 + idx], q = wfc[idx];
                accw += a.x * q.x + a.y * q.y + a.z * q.z + a.w * q.w;
            }
#pragma unroll 8
            for (int i = 0; i < 16; i++) {
                int idx = ks * 16 + i;
                float4 a = ain[128 + idx], q = wfc[128 + idx];
                accw += a.x * q.x + a.y * q.y + a.z * q.z + a.w * q.w;
            }
        }
        // ===== reader stream t+1: [x | hr] fl4 0..127 =====
        if (t + 1 < LL) {
            float accr = 0.f;
            const float4* ain = (const float4*)(arena + bln * AR);
#pragma unroll 8
            for (int i = 0; i < 32; i++) {
                int idx = ks * 32 + i;
                float4 a = ain[idx], q = rwc[idx];
                accr += a.x * q.x + a.y * q.y + a.z * q.z + a.w * q.w;
            }
            accr += __shfl_xor(accr, 8);
            accr += __shfl_xor(accr, 16);
            if (!(ln & 24)) sGr[c * 8 + bln] = accr + rb[col];
        }
        __syncthreads();   // all arena x-reads done before combine overwrites

        // ===== per-wave waitA on this wave's 8 producer flags =====
        {
            unsigned tgt = (unsigned)(t + 1);
            for (;;) {
                unsigned v = tgt;
                if (ln < 8)
                    v = __hip_atomic_load(fA + (8 * w + ln) * FSTR, __ATOMIC_RELAXED, ASCOPE);
                if (__all(v >= tgt)) break;
                __builtin_amdgcn_s_sleep(1);
            }
        }
        // ===== gather + m_rt combine (wave w handles b=bglw) -> arena x-region =====
        {
            float2 pms[8];
            float2 pva[8], pvb[8];
#pragma unroll
            for (int q2 = 0; q2 < 8; q2++) {
                int src = bg * 64 + w * 8 + q2;
                pms[q2] = ld_coh2(partMS + src * 2);
                const float* pv = partV + (size_t)src * KK + ln * 4;
                pva[q2] = ld_coh2(pv);
                pvb[q2] = ld_coh2(pv + 2);
            }
            float M = pms[0].x;
#pragma unroll
            for (int q2 = 1; q2 < 8; q2++) M = fmaxf(M, pms[q2].x);
            float S = 0.f;
            float4 V = make_float4(0.f, 0.f, 0.f, 0.f);
#pragma unroll
            for (int q2 = 0; q2 < 8; q2++) {
                float e = __expf(pms[q2].x - M);
                S += e * pms[q2].y;
                V.x += e * pva[q2].x; V.y += e * pva[q2].y;
                V.z += e * pvb[q2].x; V.w += e * pvb[q2].y;
            }
            float rS = 1.0f / S;
            ((float4*)(arena + w * AR))[ln] =
                make_float4(V.x * rS, V.y * rS, V.z * rS, V.w * rS);
            if (ln == 0) { sMS[w * 2] = M; sMS[w * 2 + 1] = S; }
        }
        __syncthreads();   // m_rt + sGr visible to all

        // ===== B-post: m_rt @ Wf2 (register weights) + reduce -> sGw =====
        {
            const float4* ain = (const float4*)(arena + bln * AR);
#pragma unroll
            for (int i = 0; i < 16; i++) {
                int idx = ks * 16 + i;
                float4 a = ain[idx];
                accw += a.x * w2[i].x + a.y * w2[i].y + a.z * w2[i].z + a.w * w2[i].w;
            }
            accw += __shfl_xor(accw, 8);
            accw += __shfl_xor(accw, 16);
            if (!(ln & 24)) sGw[c * 8 + bln] = accw;
        }
        __syncthreads();   // gates visible to wave0

        // ===== pointwise (wave0, tid<32): reader t+1 then writer t =====
        if (tid < 32) {
            int pb = tid & 7, pj = tid >> 3;
            int bgp = bg * 8 + pb;
            if (t + 1 < LL) {
                float gi = sGr[(0 + pj) * 8 + pb], gf = sGr[(4 + pj) * 8 + pb];
                float gG = sGr[(8 + pj) * 8 + pb], go = sGr[(12 + pj) * 8 + pb];
                float cn = sigf(gf) * crreg + sigf(gi) * tanhf(gG);
                float hn = sigf(go) * tanhf(cn);
                crreg = cn;
                float hn2 = __shfl(hn, tid + 8);
                if (!(pj & 1)) st_coh2(hrb[prv] + bgp * KK + j0 + pj, hn, hn2);
            }
            {
                float gi = sGw[(0 + pj) * 8 + pb], gf = sGw[(4 + pj) * 8 + pb];
                float gG = sGw[(8 + pj) * 8 + pb], go = sGw[(12 + pj) * 8 + pb];
                float cp2 = (t > 0) ? cwreg : 0.f;
                float cn = sigf(gf) * cp2 + sigf(gi) * tanhf(gG);
                float hn = sigf(go) * tanhf(cn);
                cwreg = cn;
                float hn2 = __shfl(hn, tid + 8);
                if (!(pj & 1)) {
                    st_coh2(hwb[cur] + bgp * KK + j0 + pj, hn, hn2);
                    *(float2*)(out + ((size_t)bgp * LL + t) * KK + j0 + pj) =
                        make_float2(hn, hn2);
                }
            }
        }
        bar_arrive(fBo, (unsigned)(t + 2));
        if (t + 2 < LL)
            xreg = ((const float4*)(x + ((size_t)bglw * LL + (size_t)(t + 2)) * KK))[ln];
        bar_wait(fB, (unsigned)(t + 2));
    }
}

// ---------------- host ----------------
extern "C" void kernel_launch(void* const* d_in, const int* in_sizes, int n_in,
                              void* d_out, int out_size, void* d_ws, size_t ws_size,
                              hipStream_t stream) {
    const float* x   = (const float*)d_in[0];
    const float* rWx = (const float*)d_in[1];
    const float* rWh = (const float*)d_in[2];
    const float* rb  = (const float*)d_in[3];
    const float* wWx = (const float*)d_in[4];
    const float* wWh = (const float*)d_in[5];
    const float* wb  = (const float*)d_in[6];
    const float* cW  = (const float*)d_in[7];
    const float* cb  = (const float*)d_in[8];
    float* out = (float*)d_out;

    float* ws = (float*)d_ws;
    float* WfT = ws;                        // 1024*768
    float* rWT = ws + 786432;               // 1024*512
    float* bfv = ws + 786432 + 524288;      // 1024
    float* st  = bfv + 1024;                // states + partials
    unsigned* flg = (unsigned*)(st + 98880);

    k_pre<<<932, 256, 0, stream>>>(cW, cb, wWx, wb, rWx, rWh, wWh, WfT, rWT, bfv, flg);

    const float* a_x = x; const float* a_rb = rb;
    const float* a_rWT = rWT; const float* a_WfT = WfT; const float* a_bf = bfv;
    float* a_st = st; float* a_out = out; unsigned* a_flg = flg;
    void* args[] = { &a_x, &a_rb, &a_rWT, &a_WfT, &a_bf, &a_st, &a_out, &a_flg };
    hipLaunchCooperativeKernel(reinterpret_cast<void*>(k_nse), dim3(256), dim3(512),
                               args, 0, stream);
}

// Round 10
// 13343.361 us; speedup vs baseline: 1.0612x; 1.0612x over previous
//
#include <hip/hip_runtime.h>
#include <math.h>

// NSE B=32 L=1024 K=256 — persistent kernel R10.
// vs R9: k-split interleaved at float4 granularity (idx = 4i+ks) so ks-lanes land on
// DISTINCT bank-quads (the 16-fl4 contiguous slice made ks bank-invariant: 64 dwords
// ≡ 0 mod 32 banks — R8/R9's conflict source). Weights re-paired to match.
// v4c register cache reverted (R9 spill/serialization regression).

#define Bb 32
#define LL 1024
#define KK 256
#define AR 780     // arena stride (dwords): 195 float4, ≡3 mod 8 -> bln spreads quads
#define ASCOPE __HIP_MEMORY_SCOPE_AGENT
#define FSTR 16

__device__ __forceinline__ float sigf(float v) { return 1.0f / (1.0f + __expf(-v)); }

__device__ __forceinline__ void st_coh2(float* p, float a, float b) {
    float2 v = make_float2(a, b);
    __hip_atomic_store((unsigned long long*)p,
                       __builtin_bit_cast(unsigned long long, v),
                       __ATOMIC_RELAXED, ASCOPE);
}
__device__ __forceinline__ float2 ld_coh2(const float* p) {
    unsigned long long u = __hip_atomic_load((const unsigned long long*)p,
                                             __ATOMIC_RELAXED, ASCOPE);
    return __builtin_bit_cast(float2, u);
}

__device__ __forceinline__ void bar_arrive(unsigned* fown, unsigned val) {
    asm volatile("s_waitcnt vmcnt(0) lgkmcnt(0)" ::: "memory");
    __syncthreads();
    if (threadIdx.x == 0)
        __hip_atomic_store(fown, val, __ATOMIC_RELAXED, ASCOPE);
}
__device__ __forceinline__ void bar_wait(unsigned* fbase, unsigned val) {
    if (threadIdx.x < 64) {
        for (;;) {
            unsigned v = __hip_atomic_load(fbase + threadIdx.x * FSTR,
                                           __ATOMIC_RELAXED, ASCOPE);
            if (__all(v >= val)) break;
            __builtin_amdgcn_s_sleep(1);
        }
    }
    asm volatile("" ::: "memory");
    __syncthreads();
}

// ---------------- one-time precompute (unchanged) ----------------
__global__ __launch_bounds__(256) void k_pre(
    const float* __restrict__ cW, const float* __restrict__ cb,
    const float* __restrict__ wWx, const float* __restrict__ wb,
    const float* __restrict__ rWx, const float* __restrict__ rWh,
    const float* __restrict__ wWh,
    float* __restrict__ WfT, float* __restrict__ rWT, float* __restrict__ bfv,
    unsigned* __restrict__ flg) {
    int bid = blockIdx.x, tid = threadIdx.x;
    if (bid < 512) {
        __shared__ float srow[512];
        srow[tid] = cW[(size_t)bid * 512 + tid];
        srow[256 + tid] = cW[(size_t)bid * 512 + 256 + tid];
        __syncthreads();
#pragma unroll
        for (int rep = 0; rep < 4; rep++) {
            int col = rep * 256 + tid;
            float a = 0.f;
#pragma unroll 4
            for (int c = 0; c < 512; c++) a += srow[c] * wWx[(size_t)c * 1024 + col];
            WfT[(size_t)col * 768 + bid] = a;
        }
    } else if (bid < 516) {
        int col = (bid - 512) * 256 + tid;
        float a = wb[col];
#pragma unroll 4
        for (int c = 0; c < 512; c++) a += cb[c] * wWx[(size_t)c * 1024 + col];
        bfv[col] = a;
    } else if (bid < 644) {
        int k0 = (bid - 516) * 2;
        for (int kk = k0; kk < k0 + 2; kk++)
            for (int col = tid; col < 1024; col += 256)
                rWT[(size_t)col * 512 + kk] = rWx[(size_t)kk * 1024 + col];
    } else if (bid < 772) {
        int k0 = (bid - 644) * 2;
        for (int kk = k0; kk < k0 + 2; kk++)
            for (int col = tid; col < 1024; col += 256)
                rWT[(size_t)col * 512 + 256 + kk] = rWh[(size_t)kk * 1024 + col];
    } else if (bid < 900) {
        int k0 = (bid - 772) * 2;
        for (int kk = k0; kk < k0 + 2; kk++)
            for (int col = tid; col < 1024; col += 256)
                WfT[(size_t)col * 768 + 512 + kk] = wWh[(size_t)kk * 1024 + col];
    } else {
        int idx = (bid - 900) * 256 + tid;
        flg[idx] = 0u;
    }
}

// ---------------- persistent kernel ----------------
__global__ __launch_bounds__(512, 1) void k_nse(
    const float* __restrict__ x, const float* __restrict__ rb,
    const float* __restrict__ rWT, const float* __restrict__ WfT,
    const float* __restrict__ bfv, float* __restrict__ st,
    float* __restrict__ out, unsigned* __restrict__ flg) {
    __shared__ float smem[32768 + 8 * AR + 8 + 8 + 16 + 128 + 128 + 128];
    float* memT   = smem;                 // [128][256]
    float* arena  = smem + 32768;         // [8][AR]: x/m_rt[0,256) hr[256,512) hw[512,768)
    float* sMw    = arena + 8 * AR;       // 8
    float* sSw    = sMw + 8;              // 8
    float* sMS    = sSw + 8;              // [8][2] per-b (M,S)
    float* sScore = sMS + 16;             // [8][16]
    float* sGr    = sScore + 128;         // [16][8] reader gates
    float* sGw    = sGr + 128;            // [16][8] writer gates

    float* hrb[2] = { st, st + 8192 };
    float* hwb[2] = { st + 16384, st + 24576 };
    float* partMS = st + 32832;           // [256][2]
    float* partV  = st + 33344;           // [256][256]

    int g = blockIdx.x, tid = threadIdx.x;
    int w = tid >> 6, ln = tid & 63;
    int bA = g >> 3;                      // phase-A batch
    int bg = g >> 6, gl = g & 63;
    int j0 = gl * 4;
    unsigned* fA = flg + (bg * 64) * FSTR;
    unsigned* fB = flg + (256 + bg * 64) * FSTR;
    unsigned* fAo = fA + gl * FSTR;
    unsigned* fBo = fB + gl * FSTR;

    // matvec lane map: b in low 3 bits, ks 2 bits, cp 1 bit
    int bln = ln & 7, ks = (ln >> 3) & 3, cp = ln >> 5;
    int c = 2 * w + cp;                   // 0..15 block-local col
    int gate = c >> 2, jlc = c & 3;
    int col = gate * KK + j0 + jlc;
    int bglw = bg * 8 + w;                // this wave's staging/combine batch

    const float4* wfc = (const float4*)(WfT + (size_t)col * 768);
    const float4* rwc = (const float4*)(rWT + (size_t)col * 512);
    float4 w2[16];                        // m_rt rows of col, interleaved ks slice
#pragma unroll
    for (int i = 0; i < 16; i++) w2[i] = wfc[64 + 4 * i + ks];

    float crreg = 0.f, cwreg = 0.f;       // cell states for (pb,pj) on wave0 tid<32

    // ---- prologue: memT <- x ; stage [x_0 | 0]; reader step 0 ----
    const float4* xsrc = (const float4*)(x + ((size_t)bA * LL + (size_t)(g & 7) * 128) * KK);
#pragma unroll
    for (int i = 0; i < 16; i++) ((float4*)memT)[tid + i * 512] = xsrc[tid + i * 512];
    ((float4*)(arena + w * AR))[ln] = ((const float4*)(x + (size_t)bglw * LL * KK))[ln];
    ((float4*)(arena + w * AR + 256))[ln] = make_float4(0.f, 0.f, 0.f, 0.f);
    __syncthreads();
    {
        float accr = 0.f;
        const float4* ain = (const float4*)(arena + bln * AR);
#pragma unroll 8
        for (int i = 0; i < 32; i++) {
            int idx = 4 * i + ks;
            float4 a = ain[idx], q = rwc[idx];
            accr += a.x * q.x + a.y * q.y + a.z * q.z + a.w * q.w;
        }
        accr += __shfl_xor(accr, 8);
        accr += __shfl_xor(accr, 16);
        if (!(ln & 24)) sGr[c * 8 + bln] = accr + rb[col];
    }
    __syncthreads();
    if (tid < 32) {
        int pb = tid & 7, pj = tid >> 3;
        int bgp = bg * 8 + pb;
        float gi = sGr[(0 + pj) * 8 + pb], gG = sGr[(8 + pj) * 8 + pb];
        float go = sGr[(12 + pj) * 8 + pb];
        float cn = sigf(gi) * tanhf(gG);
        float hn = sigf(go) * tanhf(cn);
        crreg = cn;
        float hn2 = __shfl(hn, tid + 8);
        if (!(pj & 1)) st_coh2(hrb[0] + bgp * KK + j0 + pj, hn, hn2);
    }
    bar_arrive(fBo, 1u);
    float4 xreg = ((const float4*)(x + ((size_t)bglw * LL + 1) * KK))[ln];
    bar_wait(fB, 1u);

    for (int t = 0; t < LL; t++) {
        int cur = t & 1, prv = cur ^ 1;
        // ===== A-top: issue MALL loads =====
        const float* hp = hrb[cur] + bA * KK + ln * 4;
        float2 ha = ld_coh2(hp), hc = ld_coh2(hp + 2);
        float4 h4 = make_float4(ha.x, ha.y, hc.x, hc.y);
        float4 hrs2, hws2, w4 = make_float4(0.f, 0.f, 0.f, 0.f);
        {
            const float* hq = hrb[cur] + bglw * KK + ln * 4;
            float2 a = ld_coh2(hq), cc = ld_coh2(hq + 2);
            hrs2 = make_float4(a.x, a.y, cc.x, cc.y);
        }
        float Mprev = 0.f, invS = 0.f;
        if (t > 0) {
            const float* wp0 = hwb[prv] + bA * KK + ln * 4;
            float2 wa = ld_coh2(wp0), wc = ld_coh2(wp0 + 2);
            w4 = make_float4(wa.x, wa.y, wc.x, wc.y);
            const float* hq = hwb[prv] + bglw * KK + ln * 4;
            float2 a = ld_coh2(hq), cc = ld_coh2(hq + 2);
            hws2 = make_float4(a.x, a.y, cc.x, cc.y);
            Mprev = sMS[(bA & 7) * 2];
            invS = 1.0f / sMS[(bA & 7) * 2 + 1];
        } else {
            hws2 = make_float4(0.f, 0.f, 0.f, 0.f);
        }
        // ===== phase A: update + dots =====
        float dp[16];
        float* rowp = memT + w * 16 * KK;
        if (t > 0) {
            float scs[16];
            const float4* sp = (const float4*)(sScore + w * 16);
#pragma unroll
            for (int q2 = 0; q2 < 4; q2++) {
                float4 s4 = sp[q2];
                scs[q2 * 4 + 0] = s4.x; scs[q2 * 4 + 1] = s4.y;
                scs[q2 * 4 + 2] = s4.z; scs[q2 * 4 + 3] = s4.w;
            }
#pragma unroll
            for (int i = 0; i < 16; i++) {
                float4* vp = (float4*)(rowp + i * KK) + ln;
                float4 v = *vp;
                float z = __expf(scs[i] - Mprev) * invS;
                float om = 1.0f - z;
                v.x = v.x * om + w4.x * z;
                v.y = v.y * om + w4.y * z;
                v.z = v.z * om + w4.z * z;
                v.w = v.w * om + w4.w * z;
                *vp = v;
                dp[i] = h4.x * v.x + h4.y * v.y + h4.z * v.z + h4.w * v.w;
            }
        } else {
#pragma unroll
            for (int i = 0; i < 16; i++) {
                float4 v = *((float4*)(rowp + i * KK) + ln);
                dp[i] = h4.x * v.x + h4.y * v.y + h4.z * v.z + h4.w * v.w;
            }
        }
        // ===== transpose-reduce, stride 9 =====
        {
            float* sT = arena + w * AR;
            int rr = ln >> 3, kk2 = ln & 7;
#pragma unroll
            for (int hh = 0; hh < 2; hh++) {
                int o = hh * 8;
#pragma unroll
                for (int j = 0; j < 8; j++) sT[ln * 9 + j] = dp[o + j];
                float ps = 0.f;
#pragma unroll
                for (int j = 0; j < 8; j++) ps += sT[(j * 8 + kk2) * 9 + rr];
                ps += __shfl_xor(ps, 1);
                ps += __shfl_xor(ps, 2);
                ps += __shfl_xor(ps, 4);
                if (kk2 == 0) sScore[w * 16 + o + rr] = ps;
            }
        }
        // ===== softmax partials (mem rows re-read, consecutive = conflict-free) =====
        {
            float scs2[16];
            const float4* sp = (const float4*)(sScore + w * 16);
#pragma unroll
            for (int q2 = 0; q2 < 4; q2++) {
                float4 s4 = sp[q2];
                scs2[q2 * 4 + 0] = s4.x; scs2[q2 * 4 + 1] = s4.y;
                scs2[q2 * 4 + 2] = s4.z; scs2[q2 * 4 + 3] = s4.w;
            }
            float M16 = scs2[0];
#pragma unroll
            for (int i = 1; i < 16; i++) M16 = fmaxf(M16, scs2[i]);
            float Sw = 0.f;
            float4 Vw = make_float4(0.f, 0.f, 0.f, 0.f);
#pragma unroll
            for (int i = 0; i < 16; i++) {
                float e = __expf(scs2[i] - M16);
                Sw += e;
                float4 v = *((float4*)(rowp + i * KK) + ln);
                Vw.x += e * v.x; Vw.y += e * v.y; Vw.z += e * v.z; Vw.w += e * v.w;
            }
            ((float4*)(arena + w * AR))[ln] = Vw;   // overwrites sT (reads done)
            if (ln == 0) { sMw[w] = M16; sSw[w] = Sw; }
        }
        __syncthreads();
        if (tid < 128) {
            float M = sMw[0];
#pragma unroll
            for (int q2 = 1; q2 < 8; q2++) M = fmaxf(M, sMw[q2]);
            float S = 0.f, V0 = 0.f, V1 = 0.f;
#pragma unroll
            for (int q2 = 0; q2 < 8; q2++) {
                float e = __expf(sMw[q2] - M);
                S += e * sSw[q2];
                V0 += e * arena[q2 * AR + 2 * tid];
                V1 += e * arena[q2 * AR + 2 * tid + 1];
            }
            st_coh2(partV + (size_t)g * KK + 2 * tid, V0, V1);
            if (tid == 0) st_coh2(partMS + g * 2, M, S);
        }
        bar_arrive(fAo, (unsigned)(t + 1));

        // ===== stage [x_{t+1} | hr_t | hw_{t-1}] into arena (per-wave b=bglw) =====
        if (t + 1 < LL) ((float4*)(arena + w * AR))[ln] = xreg;
        ((float4*)(arena + w * AR + 256))[ln] = hrs2;
        ((float4*)(arena + w * AR + 512))[ln] = hws2;
        __syncthreads();

        // ===== writer-pre stream: hr (fl4 64..127) + hw (fl4 128..191), idx=4i+ks =====
        float accw = (ks == 0) ? bfv[col] : 0.f;
        {
            const float4* ain = (const float4*)(arena + bln * AR);
#pragma unroll 8
            for (int i = 0; i < 16; i++) {
                int idx = 4 * i + ks;
                float4 a = ain[64 + idx], q = wfc[idx];
                accw += a.x * q.x + a.y * q.y + a.z * q.z + a.w * q.w;
            }
#pragma unroll 8
            for (int i = 0; i < 16; i++) {
                int idx = 4 * i + ks;
                float4 a = ain[128 + idx], q = wfc[128 + idx];
                accw += a.x * q.x + a.y * q.y + a.z * q.z + a.w * q.w;
            }
        }
        // ===== reader stream t+1: [x | hr] fl4 0..127, idx=4i+ks =====
        if (t + 1 < LL) {
            float accr = 0.f;
            const float4* ain = (const float4*)(arena + bln * AR);
#pragma unroll 8
            for (int i = 0; i < 32; i++) {
                int idx = 4 * i + ks;
                float4 a = ain[idx], q = rwc[idx];
                accr += a.x * q.x + a.y * q.y + a.z * q.z + a.w * q.w;
            }
            accr += __shfl_xor(accr, 8);
            accr += __shfl_xor(accr, 16);
            if (!(ln & 24)) sGr[c * 8 + bln] = accr + rb[col];
        }
        __syncthreads();   // all arena x-reads done before combine overwrites

        // ===== per-wave waitA on this wave's 8 producer flags =====
        {
            unsigned tgt = (unsigned)(t + 1);
            for (;;) {
                unsigned v = tgt;
                if (ln < 8)
                    v = __hip_atomic_load(fA + (8 * w + ln) * FSTR, __ATOMIC_RELAXED, ASCOPE);
                if (__all(v >= tgt)) break;
                __builtin_amdgcn_s_sleep(1);
            }
        }
        // ===== gather + m_rt combine (wave w handles b=bglw) -> arena x-region =====
        {
            float2 pms[8];
            float2 pva[8], pvb[8];
#pragma unroll
            for (int q2 = 0; q2 < 8; q2++) {
                int src = bg * 64 + w * 8 + q2;
                pms[q2] = ld_coh2(partMS + src * 2);
                const float* pv = partV + (size_t)src * KK + ln * 4;
                pva[q2] = ld_coh2(pv);
                pvb[q2] = ld_coh2(pv + 2);
            }
            float M = pms[0].x;
#pragma unroll
            for (int q2 = 1; q2 < 8; q2++) M = fmaxf(M, pms[q2].x);
            float S = 0.f;
            float4 V = make_float4(0.f, 0.f, 0.f, 0.f);
#pragma unroll
            for (int q2 = 0; q2 < 8; q2++) {
                float e = __expf(pms[q2].x - M);
                S += e * pms[q2].y;
                V.x += e * pva[q2].x; V.y += e * pva[q2].y;
                V.z += e * pvb[q2].x; V.w += e * pvb[q2].y;
            }
            float rS = 1.0f / S;
            ((float4*)(arena + w * AR))[ln] =
                make_float4(V.x * rS, V.y * rS, V.z * rS, V.w * rS);
            if (ln == 0) { sMS[w * 2] = M; sMS[w * 2 + 1] = S; }
        }
        __syncthreads();   // m_rt + sGr visible to all

        // ===== B-post: m_rt @ Wf2 (register weights, idx=4i+ks) -> sGw =====
        {
            const float4* ain = (const float4*)(arena + bln * AR);
#pragma unroll
            for (int i = 0; i < 16; i++) {
                int idx = 4 * i + ks;
                float4 a = ain[idx];
                accw += a.x * w2[i].x + a.y * w2[i].y + a.z * w2[i].z + a.w * w2[i].w;
            }
            accw += __shfl_xor(accw, 8);
            accw += __shfl_xor(accw, 16);
            if (!(ln & 24)) sGw[c * 8 + bln] = accw;
        }
        __syncthreads();   // gates visible to wave0

        // ===== pointwise (wave0, tid<32): reader t+1 then writer t =====
        if (tid < 32) {
            int pb = tid & 7, pj = tid >> 3;
            int bgp = bg * 8 + pb;
            if (t + 1 < LL) {
                float gi = sGr[(0 + pj) * 8 + pb], gf = sGr[(4 + pj) * 8 + pb];
                float gG = sGr[(8 + pj) * 8 + pb], go = sGr[(12 + pj) * 8 + pb];
                float cn = sigf(gf) * crreg + sigf(gi) * tanhf(gG);
                float hn = sigf(go) * tanhf(cn);
                crreg = cn;
                float hn2 = __shfl(hn, tid + 8);
                if (!(pj & 1)) st_coh2(hrb[prv] + bgp * KK + j0 + pj, hn, hn2);
            }
            {
                float gi = sGw[(0 + pj) * 8 + pb], gf = sGw[(4 + pj) * 8 + pb];
                float gG = sGw[(8 + pj) * 8 + pb], go = sGw[(12 + pj) * 8 + pb];
                float cp2 = (t > 0) ? cwreg : 0.f;
                float cn = sigf(gf) * cp2 + sigf(gi) * tanhf(gG);
                float hn = sigf(go) * tanhf(cn);
                cwreg = cn;
                float hn2 = __shfl(hn, tid + 8);
                if (!(pj & 1)) {
                    st_coh2(hwb[cur] + bgp * KK + j0 + pj, hn, hn2);
                    *(float2*)(out + ((size_t)bgp * LL + t) * KK + j0 + pj) =
                        make_float2(hn, hn2);
                }
            }
        }
        bar_arrive(fBo, (unsigned)(t + 2));
        if (t + 2 < LL)
            xreg = ((const float4*)(x + ((size_t)bglw * LL + (size_t)(t + 2)) * KK))[ln];
        bar_wait(fB, (unsigned)(t + 2));
    }
}

// ---------------- host ----------------
extern "C" void kernel_launch(void* const* d_in, const int* in_sizes, int n_in,
                              void* d_out, int out_size, void* d_ws, size_t ws_size,
                              hipStream_t stream) {
    const float* x   = (const float*)d_in[0];
    const float* rWx = (const float*)d_in[1];
    const float* rWh = (const float*)d_in[2];
    const float* rb  = (const float*)d_in[3];
    const float* wWx = (const float*)d_in[4];
    const float* wWh = (const float*)d_in[5];
    const float* wb  = (const float*)d_in[6];
    const float* cW  = (const float*)d_in[7];
    const float* cb  = (const float*)d_in[8];
    float* out = (float*)d_out;

    float* ws = (float*)d_ws;
    float* WfT = ws;                        // 1024*768
    float* rWT = ws + 786432;               // 1024*512
    float* bfv = ws + 786432 + 524288;      // 1024
    float* st  = bfv + 1024;                // states + partials
    unsigned* flg = (unsigned*)(st + 98880);

    k_pre<<<932, 256, 0, stream>>>(cW, cb, wWx, wb, rWx, rWh, wWh, WfT, rWT, bfv, flg);

    const float* a_x = x; const float* a_rb = rb;
    const float* a_rWT = rWT; const float* a_WfT = WfT; const float* a_bf = bfv;
    float* a_st = st; float* a_out = out; unsigned* a_flg = flg;
    void* args[] = { &a_x, &a_rb, &a_rWT, &a_WfT, &a_bf, &a_st, &a_out, &a_flg };
    hipLaunchCooperativeKernel(reinterpret_cast<void*>(k_nse), dim3(256), dim3(512),
                               args, 0, stream);
}